// Round 19
// baseline (17.517 us; speedup 1.0000x reference)
//
#include <hip/hip_runtime.h>
#include <float.h>
#include <math.h>

#define BB 8
#define PP 4096

typedef __attribute__((ext_vector_type(8))) short bf16x8;
typedef __attribute__((ext_vector_type(16))) float f32x16;

__device__ __forceinline__ unsigned int f2bf(float f) {
    unsigned int u = __float_as_uint(f);
    return (u + 0x7FFFu + ((u >> 16) & 1u)) >> 16;   // RNE bf16
}
__device__ __forceinline__ float bf2f(unsigned int h) {
    return __uint_as_float(h << 16);
}

// One block = (dir, cloud, qgroup of 256 queries) vs all 4096 neighbors.
// MFMA computes t_ji = h_j - a_i.c_j (split-precision bf16 packed into K);
// d^2 = |a|^2 + 2*min_j t.  D[j,i]: col=lane&31 (query), rows over regs/lane-half.
// SINGLE-PHASE (R17) + ROLLED LOOPS: clang's full unroll makes a ~15 KB body;
// 256 cold workgroups pay ~7.8 us of icache fill per launch (the REPEAT-probe
// intercept). Rolled main loop keeps the hand-written 2-deep pipeline but
// shrinks code to ~2 KB.
__global__ __launch_bounds__(1024) void chamfer_mfma(
    const float* __restrict__ y1, const float* __restrict__ y2,
    float* __restrict__ partial)
{
    __shared__ uint4 fbuf[2][64 * 64];   // 128 KB: A-frags for all 128 jtiles

    const int bid   = blockIdx.x;
    const int qg    = bid & 15;
    const int cloud = (bid >> 4) & 7;
    const int dir   = bid >> 7;

    const float* src = (dir == 0) ? y1 : y2;
    const float* tgt = (dir == 0) ? y2 : y1;
    const float* __restrict__ tgt_base = tgt + (size_t)cloud * PP * 3;
    const float* __restrict__ src_base = src + ((size_t)cloud * PP + (size_t)qg * 256) * 3;

    const int tid  = threadIdx.x;
    const int lane = tid & 63;
    const int w    = tid >> 6;
    const int ig   = w & 7;     // itile (32 queries) this wave owns
    const int jh   = w >> 3;    // which 64-jtile buffer this wave owns

    // ---- B-frag (queries), built once in registers ----
    // lane<32 (k0..7):  [nahix,nahiy,nahiz, nalox,naloy,naloz, nahix,nahiy]
    // lane>=32 (k8..15):[nahiz, 1.0, 1.0, 0,0,0,0,0]
    bf16x8 bfrag;
    {
        const int ql = ig * 32 + (lane & 31);
        const float ax = src_base[ql * 3 + 0];
        const float ay = src_base[ql * 3 + 1];
        const float az = src_base[ql * 3 + 2];
        const unsigned int hx = f2bf(-ax), hy = f2bf(-ay), hz = f2bf(-az);
        const unsigned int lx = f2bf(-ax - bf2f(hx));
        const unsigned int ly = f2bf(-ay - bf2f(hy));
        const unsigned int lz = f2bf(-az - bf2f(hz));
        uint4 bb;
        if (lane < 32) {
            bb.x = hx | (hy << 16);
            bb.y = hz | (lx << 16);
            bb.z = ly | (lz << 16);
            bb.w = hx | (hy << 16);
        } else {
            bb.x = hz | (0x3F80u << 16);   // k8 = nahiz, k9 = 1.0
            bb.y = 0x3F80u;                // k10 = 1.0, k11 = 0
            bb.z = 0u;
            bb.w = 0u;
        }
        bfrag = *reinterpret_cast<bf16x8*>(&bb);
    }

    float m0 = FLT_MAX, m1 = FLT_MAX, m2 = FLT_MAX, m3 = FLT_MAX;

    f32x16 zc;
    #pragma unroll
    for (int r = 0; r < 16; ++r) zc[r] = 0.0f;

#define FOLD(acc)                                          \
    do {                                                   \
        m0 = fminf(fminf(m0, (acc)[0]), (acc)[4]);         \
        m1 = fminf(fminf(m1, (acc)[1]), (acc)[5]);         \
        m2 = fminf(fminf(m2, (acc)[2]), (acc)[6]);         \
        m3 = fminf(fminf(m3, (acc)[3]), (acc)[7]);         \
        m0 = fminf(fminf(m0, (acc)[8]), (acc)[12]);        \
        m1 = fminf(fminf(m1, (acc)[9]), (acc)[13]);        \
        m2 = fminf(fminf(m2, (acc)[10]), (acc)[14]);       \
        m3 = fminf(fminf(m3, (acc)[11]), (acc)[15]);       \
    } while (0)

    // ---- Build A-frags for ALL 4096 neighbors (4/thread), ONE barrier ----
    // A lane<32 (k0..7):  [chix,chiy,chiz, chix,chiy,chiz, clox,cloy]
    // A lane>=32 (k8..15):[cloz, h_hi, h_lo, 0,0,0,0,0]
    #pragma clang loop unroll(disable)
    for (int rep = 0; rep < 4; ++rep) {
        const int n  = rep * 1024 + tid;            // 0..4095
        const float cx = tgt_base[n * 3 + 0];
        const float cy = tgt_base[n * 3 + 1];
        const float cz = tgt_base[n * 3 + 2];
        const unsigned int chx = f2bf(cx), chy = f2bf(cy), chz = f2bf(cz);
        const unsigned int clx = f2bf(cx - bf2f(chx));
        const unsigned int cly = f2bf(cy - bf2f(chy));
        const unsigned int clz = f2bf(cz - bf2f(chz));
        const float hh = 0.5f * (cx * cx + cy * cy + cz * cz);
        const unsigned int hhi = f2bf(hh);
        const unsigned int hlo = f2bf(hh - bf2f(hhi));
        const int half = n >> 11, nl = n & 2047, tile = nl >> 5, r = nl & 31;
        uint4 lof, hif;
        lof.x = chx | (chy << 16);
        lof.y = chz | (chx << 16);
        lof.z = chy | (chz << 16);
        lof.w = clx | (cly << 16);
        hif.x = clz | (hhi << 16);
        hif.y = hlo;
        hif.z = 0u;
        hif.w = 0u;
        fbuf[half][tile * 64 + r]      = lof;
        fbuf[half][tile * 64 + 32 + r] = hif;
    }
    __syncthreads();

    // ---- Main loop: 64 jtiles per wave, 2-deep pipelined fold, ROLLED ----
    {
        const uint4* __restrict__ fb = &fbuf[jh][lane];
        bf16x8 afA = *reinterpret_cast<const bf16x8*>(fb);
        f32x16 accA = __builtin_amdgcn_mfma_f32_32x32x16_bf16(afA, bfrag, zc, 0, 0, 0);
        bf16x8 afB;
        f32x16 accB;
        #pragma clang loop unroll(disable)
        for (int jt = 1; jt < 63; jt += 2) {
            afB  = *reinterpret_cast<const bf16x8*>(fb + (size_t)jt * 64);
            accB = __builtin_amdgcn_mfma_f32_32x32x16_bf16(afB, bfrag, zc, 0, 0, 0);
            FOLD(accA);                    // overlaps accB's latency
            afA  = *reinterpret_cast<const bf16x8*>(fb + (size_t)(jt + 1) * 64);
            accA = __builtin_amdgcn_mfma_f32_32x32x16_bf16(afA, bfrag, zc, 0, 0, 0);
            FOLD(accB);                    // overlaps accA's latency
        }
        afB  = *reinterpret_cast<const bf16x8*>(fb + (size_t)63 * 64);
        accB = __builtin_amdgcn_mfma_f32_32x32x16_bf16(afB, bfrag, zc, 0, 0, 0);
        FOLD(accA);
        FOLD(accB);
    }
#undef FOLD

    // ---- Epilogue: fold 4 mins, merge lane-halves, cross-jh min, distance, sum ----
    __syncthreads();   // all waves done reading fbuf before aliasing it
    float* pmin = reinterpret_cast<float*>(fbuf);   // [2][256], aliases fbuf
    float* ssum = pmin + 512;                       // 4 floats
    {
        float mm = fminf(fminf(m0, m1), fminf(m2, m3));
        mm = fminf(mm, __shfl_xor(mm, 32));
        if (lane < 32)
            pmin[jh * 256 + ig * 32 + (lane & 31)] = mm;
    }
    __syncthreads();
    if (tid < 256) {
        float v = fminf(pmin[tid], pmin[256 + tid]);
        const float ax = src_base[tid * 3 + 0];
        const float ay = src_base[tid * 3 + 1];
        const float az = src_base[tid * 3 + 2];
        const float aa = ax * ax + ay * ay + az * az;
        float d = sqrtf(fmaxf(0.0f, fmaf(2.0f, v, aa)));
        #pragma unroll
        for (int off = 32; off > 0; off >>= 1)
            d += __shfl_down(d, off);
        if ((tid & 63) == 0)
            ssum[tid >> 6] = d;
    }
    __syncthreads();
    if (tid == 0)
        partial[bid] = ssum[0] + ssum[1] + ssum[2] + ssum[3];
}

// Sum 256 block partials, normalize by B*P (gives d1 + d2).
__global__ __launch_bounds__(256) void chamfer_final(
    const float* __restrict__ partial, float* __restrict__ out)
{
    __shared__ float ssum[4];
    const int tid = threadIdx.x;
    float v = partial[tid];
    #pragma unroll
    for (int off = 32; off > 0; off >>= 1)
        v += __shfl_down(v, off);
    if ((tid & 63) == 0)
        ssum[tid >> 6] = v;
    __syncthreads();
    if (tid == 0)
        out[0] = (ssum[0] + ssum[1] + ssum[2] + ssum[3]) * (1.0f / (float)(BB * PP));
}

extern "C" void kernel_launch(void* const* d_in, const int* in_sizes, int n_in,
                              void* d_out, int out_size, void* d_ws, size_t ws_size,
                              hipStream_t stream) {
    const float* y1 = (const float*)d_in[0];
    const float* y2 = (const float*)d_in[1];
    float* partial = (float*)d_ws;    // 256 floats of scratch
    float* out     = (float*)d_out;

    chamfer_mfma<<<256, 1024, 0, stream>>>(y1, y2, partial);
    chamfer_final<<<1, 256, 0, stream>>>(partial, out);
}

// Round 20
// 17.061 us; speedup vs baseline: 1.0268x; 1.0268x over previous
//
#include <hip/hip_runtime.h>
#include <float.h>
#include <math.h>

#define BB 8
#define PP 4096

typedef __attribute__((ext_vector_type(8))) short bf16x8;
typedef __attribute__((ext_vector_type(16))) float f32x16;

__device__ __forceinline__ unsigned int f2bf(float f) {
    unsigned int u = __float_as_uint(f);
    return (u + 0x7FFFu + ((u >> 16) & 1u)) >> 16;   // RNE bf16
}
__device__ __forceinline__ float bf2f(unsigned int h) {
    return __uint_as_float(h << 16);
}

// One block = (dir, cloud, qgroup of 256 queries) vs all 4096 neighbors.
// MFMA computes t_ji = h_j - a_i.c_j (split-precision bf16 packed into K);
// d^2 = |a|^2 + 2*min_j t.  D[j,i]: col=lane&31 (query), rows over regs/lane-half.
// SINGLE-PHASE: whole cloud staged as A-frags in 128 KB LDS, ONE barrier,
// then 64 uninterrupted MFMAs/wave (2-deep pipelined fold) -> waves drift,
// MFMA and VALU overlap across waves instead of lockstep phase-bouncing.
// Session best: 17.18 us (R17). Compute is SIMD issue-port bound
// (fold = 16 v_min_f32 x 2 issue-cyc per MFMA); fixed ~9.5 us launch/tail
// overhead resists all source-level restructuring (R8/R12/R14/R19).
__global__ __launch_bounds__(1024) void chamfer_mfma(
    const float* __restrict__ y1, const float* __restrict__ y2,
    float* __restrict__ partial)
{
    __shared__ uint4 fbuf[2][64 * 64];   // 128 KB: A-frags for all 128 jtiles

    const int bid   = blockIdx.x;
    const int qg    = bid & 15;
    const int cloud = (bid >> 4) & 7;
    const int dir   = bid >> 7;

    const float* src = (dir == 0) ? y1 : y2;
    const float* tgt = (dir == 0) ? y2 : y1;
    const float* __restrict__ tgt_base = tgt + (size_t)cloud * PP * 3;
    const float* __restrict__ src_base = src + ((size_t)cloud * PP + (size_t)qg * 256) * 3;

    const int tid  = threadIdx.x;
    const int lane = tid & 63;
    const int w    = tid >> 6;
    const int ig   = w & 7;     // itile (32 queries) this wave owns
    const int jh   = w >> 3;    // which 64-jtile buffer this wave owns

    // ---- B-frag (queries), built once in registers ----
    // lane<32 (k0..7):  [nahix,nahiy,nahiz, nalox,naloy,naloz, nahix,nahiy]
    // lane>=32 (k8..15):[nahiz, 1.0, 1.0, 0,0,0,0,0]
    bf16x8 bfrag;
    {
        const int ql = ig * 32 + (lane & 31);
        const float ax = src_base[ql * 3 + 0];
        const float ay = src_base[ql * 3 + 1];
        const float az = src_base[ql * 3 + 2];
        const unsigned int hx = f2bf(-ax), hy = f2bf(-ay), hz = f2bf(-az);
        const unsigned int lx = f2bf(-ax - bf2f(hx));
        const unsigned int ly = f2bf(-ay - bf2f(hy));
        const unsigned int lz = f2bf(-az - bf2f(hz));
        uint4 bb;
        if (lane < 32) {
            bb.x = hx | (hy << 16);
            bb.y = hz | (lx << 16);
            bb.z = ly | (lz << 16);
            bb.w = hx | (hy << 16);
        } else {
            bb.x = hz | (0x3F80u << 16);   // k8 = nahiz, k9 = 1.0
            bb.y = 0x3F80u;                // k10 = 1.0, k11 = 0
            bb.z = 0u;
            bb.w = 0u;
        }
        bfrag = *reinterpret_cast<bf16x8*>(&bb);
    }

    float m0 = FLT_MAX, m1 = FLT_MAX, m2 = FLT_MAX, m3 = FLT_MAX;

    f32x16 zc;
    #pragma unroll
    for (int r = 0; r < 16; ++r) zc[r] = 0.0f;

#define FOLD(acc)                                          \
    do {                                                   \
        m0 = fminf(fminf(m0, (acc)[0]), (acc)[4]);         \
        m1 = fminf(fminf(m1, (acc)[1]), (acc)[5]);         \
        m2 = fminf(fminf(m2, (acc)[2]), (acc)[6]);         \
        m3 = fminf(fminf(m3, (acc)[3]), (acc)[7]);         \
        m0 = fminf(fminf(m0, (acc)[8]), (acc)[12]);        \
        m1 = fminf(fminf(m1, (acc)[9]), (acc)[13]);        \
        m2 = fminf(fminf(m2, (acc)[10]), (acc)[14]);       \
        m3 = fminf(fminf(m3, (acc)[11]), (acc)[15]);       \
    } while (0)

    // ---- Build A-frags for ALL 4096 neighbors (4/thread), ONE barrier ----
    // A lane<32 (k0..7):  [chix,chiy,chiz, chix,chiy,chiz, clox,cloy]
    // A lane>=32 (k8..15):[cloz, h_hi, h_lo, 0,0,0,0,0]
    #pragma unroll
    for (int rep = 0; rep < 4; ++rep) {
        const int n  = rep * 1024 + tid;            // 0..4095
        const float cx = tgt_base[n * 3 + 0];
        const float cy = tgt_base[n * 3 + 1];
        const float cz = tgt_base[n * 3 + 2];
        const unsigned int chx = f2bf(cx), chy = f2bf(cy), chz = f2bf(cz);
        const unsigned int clx = f2bf(cx - bf2f(chx));
        const unsigned int cly = f2bf(cy - bf2f(chy));
        const unsigned int clz = f2bf(cz - bf2f(chz));
        const float hh = 0.5f * (cx * cx + cy * cy + cz * cz);
        const unsigned int hhi = f2bf(hh);
        const unsigned int hlo = f2bf(hh - bf2f(hhi));
        const int half = n >> 11, nl = n & 2047, tile = nl >> 5, r = nl & 31;
        uint4 lof, hif;
        lof.x = chx | (chy << 16);
        lof.y = chz | (chx << 16);
        lof.z = chy | (chz << 16);
        lof.w = clx | (cly << 16);
        hif.x = clz | (hhi << 16);
        hif.y = hlo;
        hif.z = 0u;
        hif.w = 0u;
        fbuf[half][tile * 64 + r]      = lof;
        fbuf[half][tile * 64 + 32 + r] = hif;
    }
    __syncthreads();

    // ---- Main loop: 64 jtiles per wave, 2-deep pipelined fold, no barriers ----
    {
        const uint4* __restrict__ fb = &fbuf[jh][lane];
        bf16x8 afA = *reinterpret_cast<const bf16x8*>(fb);
        f32x16 accA = __builtin_amdgcn_mfma_f32_32x32x16_bf16(afA, bfrag, zc, 0, 0, 0);
        bf16x8 afB;
        f32x16 accB;
        for (int jt = 1; jt < 63; jt += 2) {
            afB  = *reinterpret_cast<const bf16x8*>(fb + (size_t)jt * 64);
            accB = __builtin_amdgcn_mfma_f32_32x32x16_bf16(afB, bfrag, zc, 0, 0, 0);
            FOLD(accA);                    // overlaps accB's latency
            afA  = *reinterpret_cast<const bf16x8*>(fb + (size_t)(jt + 1) * 64);
            accA = __builtin_amdgcn_mfma_f32_32x32x16_bf16(afA, bfrag, zc, 0, 0, 0);
            FOLD(accB);                    // overlaps accA's latency
        }
        afB  = *reinterpret_cast<const bf16x8*>(fb + (size_t)63 * 64);
        accB = __builtin_amdgcn_mfma_f32_32x32x16_bf16(afB, bfrag, zc, 0, 0, 0);
        FOLD(accA);
        FOLD(accB);
    }
#undef FOLD

    // ---- Epilogue: fold 4 mins, merge lane-halves, cross-jh min, distance, sum ----
    __syncthreads();   // all waves done reading fbuf before aliasing it
    float* pmin = reinterpret_cast<float*>(fbuf);   // [2][256], aliases fbuf
    float* ssum = pmin + 512;                       // 4 floats
    {
        float mm = fminf(fminf(m0, m1), fminf(m2, m3));
        mm = fminf(mm, __shfl_xor(mm, 32));
        if (lane < 32)
            pmin[jh * 256 + ig * 32 + (lane & 31)] = mm;
    }
    __syncthreads();
    if (tid < 256) {
        float v = fminf(pmin[tid], pmin[256 + tid]);
        const float ax = src_base[tid * 3 + 0];
        const float ay = src_base[tid * 3 + 1];
        const float az = src_base[tid * 3 + 2];
        const float aa = ax * ax + ay * ay + az * az;
        float d = sqrtf(fmaxf(0.0f, fmaf(2.0f, v, aa)));
        #pragma unroll
        for (int off = 32; off > 0; off >>= 1)
            d += __shfl_down(d, off);
        if ((tid & 63) == 0)
            ssum[tid >> 6] = d;
    }
    __syncthreads();
    if (tid == 0)
        partial[bid] = ssum[0] + ssum[1] + ssum[2] + ssum[3];
}

// Sum 256 block partials, normalize by B*P (gives d1 + d2).
__global__ __launch_bounds__(256) void chamfer_final(
    const float* __restrict__ partial, float* __restrict__ out)
{
    __shared__ float ssum[4];
    const int tid = threadIdx.x;
    float v = partial[tid];
    #pragma unroll
    for (int off = 32; off > 0; off >>= 1)
        v += __shfl_down(v, off);
    if ((tid & 63) == 0)
        ssum[tid >> 6] = v;
    __syncthreads();
    if (tid == 0)
        out[0] = (ssum[0] + ssum[1] + ssum[2] + ssum[3]) * (1.0f / (float)(BB * PP));
}

extern "C" void kernel_launch(void* const* d_in, const int* in_sizes, int n_in,
                              void* d_out, int out_size, void* d_ws, size_t ws_size,
                              hipStream_t stream) {
    const float* y1 = (const float*)d_in[0];
    const float* y2 = (const float*)d_in[1];
    float* partial = (float*)d_ws;    // 256 floats of scratch
    float* out     = (float*)d_out;

    chamfer_mfma<<<256, 1024, 0, stream>>>(y1, y2, partial);
    chamfer_final<<<1, 256, 0, stream>>>(partial, out);
}